// Round 9
// baseline (413.223 us; speedup 1.0000x reference)
//
#include <hip/hip_runtime.h>
#include <hip/hip_bf16.h>

constexpr int kB   = 4;
constexpr int kT   = 2048;
constexpr int kCIN = 2048;
constexpr int kHID = 1024;
constexpr int kEMB = 256;

typedef __bf16 bf16_t;
typedef __bf16 bf16x8 __attribute__((ext_vector_type(8)));
typedef __bf16 bf16x4 __attribute__((ext_vector_type(4)));
typedef float  f32x4  __attribute__((ext_vector_type(4)));

// async global->LDS 16B/lane (LDS dest = wave-uniform base + lane*16)
__device__ __forceinline__ void gll16(const void* g, void* l) {
  auto lp = reinterpret_cast<__attribute__((address_space(3))) uint32_t*>(
      reinterpret_cast<uintptr_t>(l));
  __builtin_amdgcn_global_load_lds(static_cast<const uint32_t*>(g), lp, 16, 0, 0);
}

#define MFMA_BF16 __builtin_amdgcn_mfma_f32_16x16x32_bf16

// ================= 256x256 8-phase double-buffered GEMM core ======================
// C[m,n] = sum_k A[m,k]*B[n,k] (+biasN).  512 thr = 8 waves, BK=64, Klen%64==0.
// 256 unified regs/wave (128 VGPR + 128 AGPR acc) -> 2 waves/SIMD, 1 block/CU: the
// structural register floor of a 256^2 tile.  Schedule frozen (r1-r8); staging
// rebalanced to earliest-legal phase per LDS-region lifetime: A0,B0 die at P1-end,
// B1 at P2-end, A1 at P3-end (fragments live in regs) -> stages (0,4,2,2).
// MODE 0: bf16 store; MODE 1: f32 plain store.
template <int MODE>
__device__ __forceinline__ void gemm256(bf16_t* lds, const bf16_t* A, const bf16_t* B,
                                        void* Cv, int lda, int ldb, int ldc,
                                        int m0, int n0, int Klen, const float* biasN) {
  const int tid  = threadIdx.x;
  const int lane = tid & 63, wv = tid >> 6;
  const int wm = wv & 1, wn = wv >> 1;
  const int lm = lane & 15, q = lane >> 4;
  const int l8 = lane >> 3;
  const int slot = (lane & 7) ^ l8;

  bf16_t* const sA = lds;
  bf16_t* const sB = lds + 32768;

  int aoff[4], boff[4];
#pragma unroll
  for (int cc = 0; cc < 4; cc++) {
    const int ra = cc * 64 + wv * 8 + l8;
    aoff[cc] = ra * lda;
    const int nb = ((ra >> 5) & 3) * 64 + (ra >> 7) * 32 + (ra & 31);
    boff[cc] = nb * ldb;
  }
  const bf16_t* const Ab = A + (size_t)m0 * lda + slot * 8;
  const bf16_t* const Bb = B + (size_t)n0 * ldb + slot * 8;

  const int x0 = ((q ^ (lm & 7)) << 3);
  const int x1 = (((q + 4) ^ (lm & 7)) << 3);

#define STAGE_A(T, H)                                                         \
  {                                                                           \
    bf16_t* dst_ = sA + (((T) & 1) << 14);                                    \
    const bf16_t* src_ = Ab + ((T) << 6);                                     \
    gll16(src_ + aoff[(H)], dst_ + ((H) << 12) + (wv << 9));                  \
    gll16(src_ + aoff[2 + (H)], dst_ + ((2 + (H)) << 12) + (wv << 9));        \
  }
#define STAGE_B(T, G)                                                         \
  {                                                                           \
    bf16_t* dst_ = sB + (((T) & 1) << 14);                                    \
    const bf16_t* src_ = Bb + ((T) << 6);                                     \
    gll16(src_ + boff[2 * (G)], dst_ + ((2 * (G)) << 12) + (wv << 9));        \
    gll16(src_ + boff[2 * (G) + 1], dst_ + ((2 * (G) + 1) << 12) + (wv << 9));\
  }
#define READ_A(BUF, H)                                                        \
  _Pragma("unroll") for (int i = 0; i < 4; i++) {                             \
    const bf16_t* p_ = (BUF) + ((wm * 128 + (H) * 64 + i * 16 + lm) << 6);    \
    af[i][0] = *(const bf16x8*)(p_ + x0);                                     \
    af[i][1] = *(const bf16x8*)(p_ + x1);                                     \
  }
#define READ_B(BF, BUF, G)                                                    \
  _Pragma("unroll") for (int j2 = 0; j2 < 2; j2++) {                          \
    const bf16_t* p_ = (BUF) + (((G) * 128 + wn * 32 + j2 * 16 + lm) << 6);   \
    BF[j2][0] = *(const bf16x8*)(p_ + x0);                                    \
    BF[j2][1] = *(const bf16x8*)(p_ + x1);                                    \
  }
#define QUAD(H, G, BF)                                                        \
  _Pragma("unroll") for (int i2 = 0; i2 < 4; i2++)                            \
  _Pragma("unroll") for (int j2 = 0; j2 < 2; j2++)                            \
  _Pragma("unroll") for (int kk = 0; kk < 2; kk++)                            \
    acc[(H) * 4 + i2][(G) * 2 + j2] = MFMA_BF16(                              \
        af[i2][kk], BF[j2][kk], acc[(H) * 4 + i2][(G) * 2 + j2], 0, 0, 0);
#define MFMA_OPEN()                                                           \
  asm volatile("s_waitcnt lgkmcnt(0)" ::: "memory");                          \
  __builtin_amdgcn_s_setprio(1);
#define MFMA_CLOSE() __builtin_amdgcn_s_setprio(0);

  f32x4 acc[8][4];
#pragma unroll
  for (int i = 0; i < 8; i++)
#pragma unroll
    for (int j = 0; j < 4; j++)
#pragma unroll
      for (int r = 0; r < 4; r++) acc[i][j][r] = 0.f;

  const int nt = Klen >> 6;

  STAGE_A(0, 0) STAGE_B(0, 0) STAGE_B(0, 1) STAGE_A(0, 1)
  STAGE_A(1, 0) STAGE_B(1, 0) STAGE_B(1, 1) STAGE_A(1, 1)
  asm volatile("s_waitcnt vmcnt(8)" ::: "memory");
  __builtin_amdgcn_s_barrier();

  bf16x8 af[4][2], bf0[2][2], bf1[2][2];
  for (int t = 0; t < nt; t++) {
    bf16_t* const a = sA + ((t & 1) << 14);
    bf16_t* const b = sB + ((t & 1) << 14);
    const bool pf = (t + 2) < nt;
    // P1: read A-half0 + B-group0 (12 b128); MFMA quadrant (0,0)
    READ_A(a, 0)
    READ_B(bf0, b, 0)
    asm volatile("s_waitcnt lgkmcnt(8)" ::: "memory");
    __builtin_amdgcn_s_barrier();
    MFMA_OPEN()
    QUAD(0, 0, bf0)
    MFMA_CLOSE()
    __builtin_amdgcn_s_barrier();
    // P2: read B-group1 (4 b128); prefetch A0+B0(t+2) (regions died at P1-end)
    READ_B(bf1, b, 1)
    if (pf) { STAGE_A(t + 2, 0) STAGE_B(t + 2, 0) }
    __builtin_amdgcn_s_barrier();
    MFMA_OPEN()
    QUAD(0, 1, bf1)
    MFMA_CLOSE()
    __builtin_amdgcn_s_barrier();
    // P3: read A-half1 (8 b128); prefetch B1(t+2) (died at P2-end)
    READ_A(a, 1)
    if (pf) STAGE_B(t + 2, 1)
    __builtin_amdgcn_s_barrier();
    MFMA_OPEN()
    QUAD(1, 1, bf1)
    MFMA_CLOSE()
    __builtin_amdgcn_s_barrier();
    // P4: prefetch A1(t+2) (died at P3-end); reg-only MFMA
    if (pf) STAGE_A(t + 2, 1)
    __builtin_amdgcn_s_barrier();
    __builtin_amdgcn_s_setprio(1);
    QUAD(1, 0, bf0)
    __builtin_amdgcn_s_setprio(0);
    if (pf)
      asm volatile("s_waitcnt vmcnt(8)" ::: "memory");
    else if (t + 1 < nt)
      asm volatile("s_waitcnt vmcnt(0)" ::: "memory");
    __builtin_amdgcn_s_barrier();
  }

#pragma unroll
  for (int i = 0; i < 8; i++) {
    const int gm = m0 + wm * 128 + (i >> 2) * 64 + (i & 3) * 16 + q * 4;
#pragma unroll
    for (int j = 0; j < 4; j++) {
      const int gn = n0 + wn * 64 + j * 16 + lm;
      const float bn_ = biasN ? biasN[gn] : 0.f;
#pragma unroll
      for (int r = 0; r < 4; r++) {
        const float v = acc[i][j][r] + bn_;
        const size_t idx = (size_t)(gm + r) * ldc + gn;
        if (MODE == 0) ((bf16_t*)Cv)[idx] = (bf16_t)v;
        else           ((float*)Cv)[idx] = v;
      }
    }
  }
#undef STAGE_A
#undef STAGE_B
#undef READ_A
#undef READ_B
#undef QUAD
#undef MFMA_OPEN
#undef MFMA_CLOSE
}

// mirror-late predicate: the 20 S1 tiles computed via split-K (z==3, local>=16)
__device__ __forceinline__ bool mirror_is_late(int z, int qq, int p) {
  const int R = qq >> 2, C = p >> 2;
  const int local = 8 * R - (R * (R - 1)) / 2 + (C - R);
  return (z == 3) && (local >= 16);
}

// ======= dispatch 1: prep — wide casts (8 elem/thr, bf16x8 stores) + rest =========
__global__ __launch_bounds__(256) void k_prep(const float* __restrict__ x,
                                              const float* __restrict__ th,
                                              const float* __restrict__ ph,
                                              const float* __restrict__ g,
                                              const float* __restrict__ emb,
                                              const float* __restrict__ w_w,
                                              const float* __restrict__ w_b,
                                              const float* __restrict__ emb_b,
                                              const float* __restrict__ tb,
                                              const float* __restrict__ pb,
                                              const float* __restrict__ gb,
                                              bf16_t* __restrict__ xbf,
                                              bf16_t* __restrict__ wqkv,
                                              bf16_t* __restrict__ embbf,
                                              bf16_t* __restrict__ wwT,
                                              float* __restrict__ biase,
                                              float* __restrict__ bqkv) {
  __shared__ float tile[64 * 66];
  const int b = blockIdx.x;
  if (b < 11520) {  // casts: 2048 elems/block, 16B loads x2 + 16B store
    const float* in; bf16_t* o; long i;
    if (b < 8192)       { in = x;   o = xbf;                            i = (long)b * 2048; }
    else if (b < 9216)  { in = th;  o = wqkv;                           i = (long)(b - 8192) * 2048; }
    else if (b < 10240) { in = ph;  o = wqkv + (size_t)kHID * kCIN;     i = (long)(b - 9216) * 2048; }
    else if (b < 11264) { in = g;   o = wqkv + (size_t)2 * kHID * kCIN; i = (long)(b - 10240) * 2048; }
    else                { in = emb; o = embbf;                          i = (long)(b - 11264) * 2048; }
    i += (long)threadIdx.x * 8;
    float4 v0 = ((const float4*)(in + i))[0];
    float4 v1 = ((const float4*)(in + i))[1];
    bf16x8 ov;
    ov[0] = (bf16_t)v0.x; ov[1] = (bf16_t)v0.y; ov[2] = (bf16_t)v0.z; ov[3] = (bf16_t)v0.w;
    ov[4] = (bf16_t)v1.x; ov[5] = (bf16_t)v1.y; ov[6] = (bf16_t)v1.z; ov[7] = (bf16_t)v1.w;
    *(bf16x8*)(o + i) = ov;
  } else if (b < 12032) {  // w_w (CIN,HID) -> wwT (HID,CIN)
    int j = b - 11520;
    int h0 = (j & 15) * 64, c0 = (j >> 4) * 64;
#pragma unroll
    for (int k = 0; k < 16; k++) {
      int e = k * 256 + threadIdx.x;
      int r = e >> 6, c = e & 63;
      tile[r * 66 + c] = w_w[(size_t)(c0 + r) * kHID + h0 + c];
    }
    __syncthreads();
#pragma unroll
    for (int k = 0; k < 16; k++) {
      int e = k * 256 + threadIdx.x;
      int r = e >> 6, c = e & 63;
      wwT[(size_t)(h0 + r) * kCIN + c0 + c] = (bf16_t)tile[c * 66 + r];
    }
  } else if (b < 12288) {  // bias_e = emb @ w_b + emb_b
    int e = b - 12032;
    float acc = 0.f;
    for (int c = threadIdx.x; c < kCIN; c += 256)
      acc += emb[(size_t)e * kCIN + c] * w_b[c];
#pragma unroll
    for (int o = 32; o > 0; o >>= 1) acc += __shfl_xor(acc, o, 64);
    __syncthreads();
    if ((threadIdx.x & 63) == 0) tile[threadIdx.x >> 6] = acc;
    __syncthreads();
    if (threadIdx.x == 0) biase[e] = tile[0] + tile[1] + tile[2] + tile[3] + emb_b[e];
  } else {  // concat biases -> bqkv[3072]
    int i = (b - 12288) * 256 + threadIdx.x;
    if (i < 3072)
      bqkv[i] = i < 1024 ? tb[i] : (i < 2048 ? pb[i - 1024] : gb[i - 2048]);
  }
}

// ========== dispatch 2: QKV(384) + S1-full(124) + M(4) = 512 = 2 EXACT rounds =====
__global__ __launch_bounds__(512, 2) void k_mega1(const bf16_t* __restrict__ xbf,
                                                  const bf16_t* __restrict__ wqkv,
                                                  const bf16_t* __restrict__ embbf,
                                                  const bf16_t* __restrict__ wwT,
                                                  bf16_t* __restrict__ xtphi,
                                                  bf16_t* __restrict__ S1,
                                                  bf16_t* __restrict__ Mbf,
                                                  const float* __restrict__ bqkv) {
  __shared__ bf16_t lds[65536];
  const int bid = blockIdx.x;
  if (bid < 384) {  // xtphi = x @ wqkv^T + bqkv (8192 x 3072, K=2048)
    const int bm = bid & 31, bn = bid >> 5;
    gemm256<0>(lds, xbf, wqkv, xtphi, 2048, 2048, 3072,
               bm * 256, bn * 256, 2048, bqkv);
  } else if (bid < 508) {  // S1 full tiles: s = 0..123
    int s = bid - 384;
    const int z = s / 36;
    int tt = s % 36, rr = 0;
    while (tt >= 8 - rr) { tt -= 8 - rr; rr++; }
    const bf16_t* Az = xbf + (size_t)z * kT * kCIN;
    gemm256<0>(lds, Az, Az, S1 + (size_t)z * kT * kT, 2048, 2048, 2048,
               rr * 256, (rr + tt) * 256, 2048, nullptr);
  } else {  // M = emb @ w_w (256 x 1024, K=2048)
    const int m = bid - 508;
    gemm256<0>(lds, embbf, wwT, Mbf, 2048, 2048, 1024, 0, m * 256, 2048, nullptr);
  }
}

// ====== dispatch 3: S2(256, round 1) + W-quarters(64) + S1-quarters(80) ===========
__global__ __launch_bounds__(512, 2) void k_gemm2(const bf16_t* __restrict__ xtphi,
                                                  bf16_t* __restrict__ S2,
                                                  const bf16_t* __restrict__ Mbf,
                                                  float* __restrict__ Wf,
                                                  const bf16_t* __restrict__ xbf,
                                                  float* __restrict__ S1f) {
  __shared__ bf16_t lds[65536];
  const int bid = blockIdx.x;
  if (bid < 256) {  // S2[z] = xphi[z] @ xt[z]^T (K=1024)
    const int bm = bid & 7, bn = (bid >> 3) & 7, z = bid >> 6;
    const bf16_t* base = xtphi + (size_t)z * kT * 3072;
    gemm256<0>(lds, base + 1024, base, S2 + (size_t)z * kT * kT, 3072, 3072, 2048,
               bm * 256, bn * 256, 1024, nullptr);
  } else if (bid < 320) {  // W quarters: wj = 0..63; tile = wj&31, ks = wj>>5
    const int wj = bid - 256;
    const int tle = wj & 31, ks = wj >> 5;
    const int z = tle >> 3, ntile = tle & 7;
    gemm256<1>(lds, Mbf + ks * 512,
               xtphi + (size_t)(z * kT + ntile * 256) * 3072 + 2048 + ks * 512,
               Wf + (size_t)(ks * 32 + tle) * 65536, 1024, 3072, 256, 0, 0, 512,
               nullptr);
  } else {  // S1 quarters: qj = 0..79; s = 124 + qj/4, K-slice ks = qj&3
    const int qj = bid - 320;
    const int s = 124 + (qj >> 2), ks = qj & 3;
    const int z = s / 36;
    int tt = s % 36, rr = 0;
    while (tt >= 8 - rr) { tt -= 8 - rr; rr++; }
    const bf16_t* Az = xbf + (size_t)z * kT * kCIN;
    gemm256<1>(lds, Az + (size_t)(rr * 256) * 2048 + ks * 512,
               Az + (size_t)((rr + tt) * 256) * 2048 + ks * 512,
               S1f + (size_t)qj * 65536, 2048, 2048, 256, 0, 0, 512, nullptr);
  }
}

// ====== dispatch 4 (256-thr, high-occ): S1 cast+sym-transpose(320) + ==============
// ====== mirror-nonlate(1984 gated) + W-combine(1024) = 3328 blocks ================
__global__ __launch_bounds__(256) void k_util2(bf16_t* __restrict__ S1,
                                               const float* __restrict__ S1f,
                                               const float* __restrict__ Wf,
                                               bf16_t* __restrict__ W) {
  __shared__ bf16_t tile[64 * 66];
  const int bid = blockIdx.x;
  const size_t T2 = (size_t)kT * kT;
  if (bid < 320) {  // late-tile 64x64 sub-block: sum 4 partials -> upper + lower^T
    const int t20 = bid >> 4, sb = bid & 15;
    const int sr = sb >> 2, sc = sb & 3;
    const int s = 124 + t20;
    const int z = s / 36;
    int tt = s % 36, rr = 0;
    while (tt >= 8 - rr) { tt -= 8 - rr; rr++; }
    const int cc = rr + tt;
    if (tt == 0 && sr > sc) return;
    const int r = threadIdx.x >> 2, c0 = (threadIdx.x & 3) << 4;
    const float* base = S1f + (size_t)(4 * t20) * 65536 +
                        (size_t)(sr * 64 + r) * 256 + sc * 64 + c0;
    float v[16];
#pragma unroll
    for (int k = 0; k < 16; k++) v[k] = 0.f;
#pragma unroll
    for (int ks = 0; ks < 4; ks++) {
      const float* p = base + (size_t)ks * 65536;
#pragma unroll
      for (int q4 = 0; q4 < 4; q4++) {
        f32x4 t4 = *(const f32x4*)(p + q4 * 4);
#pragma unroll
        for (int k = 0; k < 4; k++) v[q4 * 4 + k] += t4[k];
      }
    }
    bf16x8 o0, o1;
#pragma unroll
    for (int k = 0; k < 8; k++) { o0[k] = (bf16_t)v[k]; o1[k] = (bf16_t)v[8 + k]; }
    const size_t zb = (size_t)z * T2;
    bf16_t* up = S1 + zb + (size_t)(rr * 256 + sr * 64 + r) * kT + cc * 256 + sc * 64 + c0;
    *(bf16x8*)up = o0;
    *(bf16x8*)(up + 8) = o1;
    if (tt == 0 && sr == sc) return;
#pragma unroll
    for (int k = 0; k < 8; k++) {
      tile[r * 66 + c0 + k]     = o0[k];
      tile[r * 66 + c0 + 8 + k] = o1[k];
    }
    __syncthreads();
    bf16x8 w0, w1;
#pragma unroll
    for (int k = 0; k < 8; k++) {
      w0[k] = tile[(c0 + k) * 66 + r];
      w1[k] = tile[(c0 + 8 + k) * 66 + r];
    }
    bf16_t* lo = S1 + zb + (size_t)(cc * 256 + sc * 64 + r) * kT + rr * 256 + sr * 64 + c0;
    *(bf16x8*)lo = w0;
    *(bf16x8*)(lo + 8) = w1;
  } else if (bid < 2304) {  // mirror S1 upper->lower, NON-late 64x64 blocks
    int j = bid - 320;
    int z = j / 496, t = j % 496, qq = 0;
    while (t >= 31 - qq) { t -= 31 - qq; qq++; }
    int p = qq + 1 + t;
    if (mirror_is_late(z, qq, p)) return;
    const size_t base = (size_t)z * T2;
#pragma unroll
    for (int k = 0; k < 16; k++) {
      int e = k * 256 + threadIdx.x;
      int r = e >> 6, c = e & 63;
      tile[r * 66 + c] = S1[base + (size_t)(qq * 64 + r) * kT + p * 64 + c];
    }
    __syncthreads();
#pragma unroll
    for (int k = 0; k < 16; k++) {
      int e = k * 256 + threadIdx.x;
      int r = e >> 6, c = e & 63;
      S1[base + (size_t)(p * 64 + r) * kT + qq * 64 + c] = tile[c * 66 + r];
    }
  } else {  // W combine: 1024 blocks x 2048 elems
    const long i = (long)(bid - 2304) * 2048 + threadIdx.x * 8;
    const int tle = (int)(i >> 16), w = (int)(i & 65535);
    const float* a = Wf + (size_t)tle * 65536 + w;
    const float* b = a + (size_t)32 * 65536;
    f32x4 lo = *(const f32x4*)a, hi = *(const f32x4*)(a + 4);
    f32x4 l2 = *(const f32x4*)b, h2 = *(const f32x4*)(b + 4);
    const int e = w >> 8, sl = w & 255;
    bf16x8 o;
#pragma unroll
    for (int k = 0; k < 4; k++) {
      o[k]     = (bf16_t)(lo[k] + l2[k]);
      o[4 + k] = (bf16_t)(hi[k] + h2[k]);
    }
    *(bf16x8*)(W + (size_t)(tle >> 3) * kEMB * kT + (size_t)e * kT + (tle & 7) * 256 + sl) = o;
  }
}

// ============ dispatch 5: moca — wave-per-row, register-resident ==================
__global__ __launch_bounds__(256) void k_moca(const bf16_t* __restrict__ S1,
                                              const bf16_t* __restrict__ S2,
                                              bf16_t* __restrict__ dst,
                                              const float* __restrict__ rou_w,
                                              const float* __restrict__ rou_b) {
  const int wv = threadIdx.x >> 6, lane = threadIdx.x & 63;
  const int t = blockIdx.x * 4 + wv, b = blockIdx.y;
  const size_t T2 = (size_t)kT * kT;
  const bf16_t* src = (b < 2) ? S1 : S2;
  const int pb = (b < 2) ? 2 * b : 2 * (b - 2);
  const bf16_t* rA = src + (size_t)pb * T2 + (size_t)t * kT;
  const bf16_t* rB = rA + T2;

  float va[32], vb[32];
#pragma unroll
  for (int c = 0; c < 4; c++) {
    bf16x8 a  = *(const bf16x8*)(rA + c * 512 + lane * 8);
    bf16x8 bb = *(const bf16x8*)(rB + c * 512 + lane * 8);
#pragma unroll
    for (int k = 0; k < 8; k++) { va[c * 8 + k] = (float)a[k]; vb[c * 8 + k] = (float)bb[k]; }
  }
  auto wmax = [](float v) {
#pragma unroll
    for (int o = 32; o > 0; o >>= 1) v = fmaxf(v, __shfl_xor(v, o, 64));
    return v;
  };
  auto wsum = [](float v) {
#pragma unroll
    for (int o = 32; o > 0; o >>= 1) v += __shfl_xor(v, o, 64);
    return v;
  };

  float m = -1e30f, s;
#pragma unroll
  for (int j = 0; j < 32; j++) m = fmaxf(m, va[j]);
  m = wmax(m); s = 0.f;
#pragma unroll
  for (int j = 0; j < 32; j++) { va[j] = __expf(va[j] - m); s += va[j]; }
  const float invA = 1.f / wsum(s);

  m = -1e30f;
#pragma unroll
  for (int j = 0; j < 32; j++) m = fmaxf(m, vb[j]);
  m = wmax(m); s = 0.f;
#pragma unroll
  for (int j = 0; j < 32; j++) { vb[j] = __expf(vb[j] - m); s += vb[j]; }
  const float invB = 1.f / wsum(s);

  const float r0 = rou_w[0], r1 = rou_w[1], rb2 = rou_b[0];
#pragma unroll
  for (int j = 0; j < 32; j++) va[j] = r0 * va[j] * invA + r1 * vb[j] * invB + rb2;

  m = -1e30f;
#pragma unroll
  for (int j = 0; j < 32; j++) m = fmaxf(m, va[j]);
  m = wmax(m); s = 0.f;
#pragma unroll
  for (int j = 0; j < 32; j++) { va[j] = __expf(va[j] - m); s += va[j]; }
  const float invC = 1.f / wsum(s);

  bf16_t* o = dst + (size_t)b * T2 + (size_t)t * kT;
#pragma unroll
  for (int c = 0; c < 4; c++) {
    bf16x8 ov;
#pragma unroll
    for (int k = 0; k < 8; k++) ov[k] = (bf16_t)(va[c * 8 + k] * invC);
    *(bf16x8*)(o + c * 512 + lane * 8) = ov;
  }
}

// ============ dispatch 6: mocab -> mocaT (128x64 tiles, 2048 blocks) ==============
__global__ __launch_bounds__(256) void k_mocaT(const bf16_t* __restrict__ in,
                                               bf16_t* __restrict__ out) {
  __shared__ bf16_t tile[128 * 66];
  size_t base = (size_t)blockIdx.z * kT * kT;
  int r0 = blockIdx.y * 128, c0 = blockIdx.x * 64;
#pragma unroll
  for (int k = 0; k < 32; k++) {
    int e = k * 256 + threadIdx.x;
    int r = e >> 6, c = e & 63;
    tile[r * 66 + c] = in[base + (size_t)(r0 + r) * kT + c0 + c];
  }
  __syncthreads();
#pragma unroll
  for (int k = 0; k < 32; k++) {
    int e = k * 256 + threadIdx.x;
    int r2 = e >> 7, c2 = e & 127;
    out[base + (size_t)(c0 + r2) * kT + r0 + c2] = tile[c2 * 66 + r2];
  }
}

// ====== dispatch 7: out slices — 128 jobs K=1024 (4 partial slices total) =========
__global__ __launch_bounds__(512, 2) void k_outq(const bf16_t* __restrict__ mocaT,
                                                 const bf16_t* __restrict__ W,
                                                 const bf16_t* __restrict__ xbf,
                                                 const bf16_t* __restrict__ embbf,
                                                 float* __restrict__ outf) {
  __shared__ bf16_t lds[65536];
  const int bid = blockIdx.x;
  if (bid < 64) {
    const int m = bid & 31, kh = bid >> 5;
    const int z = m >> 3;
    gemm256<1>(lds,
               mocaT + (size_t)z * kT * kT + (size_t)((m & 7) * 256) * kT + kh * 1024,
               W + (size_t)z * kEMB * kT + kh * 1024,
               outf + (size_t)kh * 2097152 + (size_t)m * 65536,
               2048, 2048, 256, 0, 0, 1024, nullptr);
  } else {
    const int r = bid - 64;
    const int m = r & 31, kh = r >> 5;
    gemm256<1>(lds,
               xbf + (size_t)(m * 256) * kCIN + kh * 1024,
               embbf + kh * 1024,
               outf + (size_t)(2 + kh) * 2097152 + (size_t)m * 65536,
               2048, 2048, 256, 0, 0, 1024, nullptr);
  }
}

// ================= dispatch 8: out = sum of 4 partials + biase ====================
__global__ __launch_bounds__(256) void k_fin(const float* __restrict__ outf,
                                             const float* __restrict__ biase,
                                             float* __restrict__ out) {
  const long i = (long)blockIdx.x * 2048 + threadIdx.x * 8;
  const int e0 = (int)(i & 255);
  f32x4 lo = {0.f, 0.f, 0.f, 0.f}, hi = {0.f, 0.f, 0.f, 0.f};
#pragma unroll
  for (int ks = 0; ks < 4; ks++) {
    const float* p = outf + (size_t)ks * 2097152 + i;
    f32x4 l2 = *(const f32x4*)p, h2 = *(const f32x4*)(p + 4);
#pragma unroll
    for (int k = 0; k < 4; k++) { lo[k] += l2[k]; hi[k] += h2[k]; }
  }
#pragma unroll
  for (int k = 0; k < 4; k++) {
    lo[k] += biase[e0 + k];
    hi[k] += biase[e0 + 4 + k];
  }
  *(f32x4*)(out + i) = lo;
  *(f32x4*)(out + i + 4) = hi;
}

extern "C" void kernel_launch(void* const* d_in, const int* in_sizes, int n_in,
                              void* d_out, int out_size, void* d_ws, size_t ws_size,
                              hipStream_t stream) {
  const float* x       = (const float*)d_in[0];
  const float* theta_w = (const float*)d_in[1];
  const float* theta_b = (const float*)d_in[2];
  const float* phi_w   = (const float*)d_in[3];
  const float* phi_b   = (const float*)d_in[4];
  const float* g_w     = (const float*)d_in[5];
  const float* g_b     = (const float*)d_in[6];
  const float* rou_w   = (const float*)d_in[7];
  const float* rou_b   = (const float*)d_in[8];
  const float* w_w     = (const float*)d_in[9];
  const float* w_b     = (const float*)d_in[10];
  const float* emb_w   = (const float*)d_in[11];
  const float* emb_b   = (const float*)d_in[12];
  float* out = (float*)d_out;

  char* ws = (char*)d_ws;
  size_t off = 0;
  auto alloc = [&](size_t bytes) -> char* {
    off = (off + 255) & ~(size_t)255;
    char* p = ws + off;
    off += bytes;
    return p;
  };

  const size_t BT = (size_t)kB * kT;   // 8192
  const size_t T2 = (size_t)kT * kT;   // 4M

  bf16_t* xbf   = (bf16_t*)alloc(BT * kCIN * 2);               // 33.5 MB
  bf16_t* wqkv  = (bf16_t*)alloc((size_t)3 * kHID * kCIN * 2); // 12.6 MB
  bf16_t* embbf = (bf16_t*)alloc((size_t)kEMB * kCIN * 2);     // 1.0 MB
  bf16_t* wwT   = (bf16_t*)alloc((size_t)kHID * kCIN * 2);     // 4.2 MB
  bf16_t* xtphi = (bf16_t*)alloc(BT * 3072 * 2);               // 50.3 MB [xt|xphi|xg]
  float*  Wf    = (float*)alloc((size_t)64 * 65536 * 4);       // 16.8 MB (W partials)
  bf16_t* mocab = (bf16_t*)alloc((size_t)kB * T2 * 2);         // 33.5 MB
  bf16_t* Mbf   = (bf16_t*)alloc((size_t)kEMB * kHID * 2);     // 0.5 MB
  bf16_t* W     = (bf16_t*)alloc((size_t)kB * kEMB * kT * 2);  // 4.2 MB
  float*  biase = (float*)alloc((size_t)kEMB * 4);
  float*  bqkv  = (float*)alloc((size_t)3072 * 4);
  bf16_t* S1    = (bf16_t*)alloc((size_t)kB * T2 * 2);         // 33.5 MB
  bf16_t* S2    = (bf16_t*)alloc((size_t)kB * T2 * 2);         // 33.5 MB
  // aliases over dead regions:
  bf16_t* mocaT = (bf16_t*)xtphi;  // xtphi dead after k_gemm2 (S2 + W reads)
  float*  S1f   = (float*)mocab;   // read in k_util2; mocab written later (k_moca)
  float*  outf  = (float*)S1;      // 4 x 8.4 MB = 33.5 MB = S1 (dead after k_moca)

  // 1: prep (wide casts + wwT + bias_e + bqkv)
  k_prep<<<dim3(12300), 256, 0, stream>>>(x, theta_w, phi_w, g_w, emb_w, w_w, w_b,
                                          emb_b, theta_b, phi_b, g_b,
                                          xbf, wqkv, embbf, wwT, biase, bqkv);
  // 2: QKV + S1-full + M = 512 jobs = 2 exact rounds
  k_mega1<<<dim3(512), 512, 0, stream>>>(xbf, wqkv, embbf, wwT, xtphi, S1, Mbf, bqkv);
  // 3: S2 (round 1) + W-quarters + S1-quarters (round 2)
  k_gemm2<<<dim3(400), 512, 0, stream>>>(xtphi, S2, Mbf, Wf, xbf, S1f);
  // 4: S1 cast+sym-transpose + mirror(non-late) + W combine (high-occ)
  k_util2<<<dim3(3328), 256, 0, stream>>>(S1, S1f, Wf, W);
  // 5: moca (both passes, wave-per-row)
  k_moca<<<dim3(kT / 4, kB), 256, 0, stream>>>(S1, S2, mocab, rou_w, rou_b);
  // 6: mocaT (128x64 tiles, overwrites dead xtphi)
  k_mocaT<<<dim3(32, 16, kB), 256, 0, stream>>>(mocab, mocaT);
  // 7: out slices (128 K=1024 jobs -> 4 f32 partial slices over dead S1)
  k_outq<<<dim3(128), 512, 0, stream>>>(mocaT, W, xbf, embbf, outf);
  // 8: out = sum partials + biase
  k_fin<<<dim3(1024), 256, 0, stream>>>(outf, biase, out);
}